// Round 3
// baseline (282.397 us; speedup 1.0000x reference)
//
#include <hip/hip_runtime.h>

// Prototype loss: loss = 0.5*mean_B( mean_D((x-p)^2) ) + 0.5*mean_B( 1 - cos(x,p) )
// x: [B, 512] f32, label: [B] i32, proto: [1000, 512] f32, out: scalar f32.
//
// R3: single-pass with fused finish.
//  - 16 lanes per row, 4 rows in flight per wave (16 indep float4 loads/lane -> high MLP)
//  - per-block partial -> device-scope atomicAdd into ws ctl block
//  - last finishing block (completion counter) writes the scalar output
//  - tiny init kernel zeroes the 8-byte ctl (d_ws is poisoned 0xAA every call)

constexpr int D_DIM   = 512;
constexpr float COS_EPS = 1e-8f;
constexpr int NBLOCKS = 2048;
constexpr int G       = 16;                   // lanes per row
constexpr int F4      = (D_DIM / 4) / G;      // 8 float4 per lane per row
constexpr int RPP     = 64 / G;               // 4 rows per wave per pass

struct WsCtl {
    float    acc;
    unsigned cnt;
};

__global__ __launch_bounds__(64) void proto_loss_init(WsCtl* ctl) {
    if (threadIdx.x == 0) {
        ctl->acc = 0.0f;
        ctl->cnt = 0u;
    }
}

__global__ __launch_bounds__(256) void proto_loss_main(
    const float* __restrict__ x,
    const int* __restrict__ label,
    const float* __restrict__ proto,
    WsCtl* __restrict__ ctl,
    int B, float invB)
{
    const int lane = threadIdx.x & 63;
    const int wave = threadIdx.x >> 6;
    const int sub  = lane & (G - 1);          // 0..15 within row group
    const int grp  = lane >> 4;               // 0..3: which row of the pass
    const int wavesPerBlock = blockDim.x >> 6;               // 4
    const int gwave  = blockIdx.x * wavesPerBlock + wave;
    const int nwaves = gridDim.x * wavesPerBlock;            // 8192

    const int rowsPerWave = (B + nwaves - 1) / nwaves;       // 8 for B=65536
    const int base = gwave * rowsPerWave;

    float acc = 0.0f;

    // prefetch first pass's label
    int row  = base + grp;
    int lbl  = (row < B) ? label[row] : 0;

    for (int r0 = 0; r0 < rowsPerWave; r0 += RPP) {
        const int nrow = base + r0 + RPP + grp;              // next pass's row
        const int nlbl = (nrow < B) ? label[nrow] : 0;       // prefetch

        if (row < B) {
            const float4* __restrict__ xr =
                reinterpret_cast<const float4*>(x + (size_t)row * D_DIM);
            const float4* __restrict__ pr =
                reinterpret_cast<const float4*>(proto + (size_t)lbl * D_DIM);

            float dot = 0.0f, sx = 0.0f, sp = 0.0f;
            #pragma unroll
            for (int k = 0; k < F4; ++k) {
                float4 xv = xr[sub + k * G];
                float4 pv = pr[sub + k * G];
                dot += xv.x*pv.x + xv.y*pv.y + xv.z*pv.z + xv.w*pv.w;
                sx  += xv.x*xv.x + xv.y*xv.y + xv.z*xv.z + xv.w*xv.w;
                sp  += pv.x*pv.x + pv.y*pv.y + pv.z*pv.z + pv.w*pv.w;
            }

            #pragma unroll
            for (int off = G / 2; off > 0; off >>= 1) {
                dot += __shfl_down(dot, off, G);
                sx  += __shfl_down(sx,  off, G);
                sp  += __shfl_down(sp,  off, G);
            }

            if (sub == 0) {
                float sse   = sx - 2.0f * dot + sp;
                float denom = fmaxf(sqrtf(sx) * sqrtf(sp), COS_EPS);
                acc += 0.5f * (sse * (1.0f / D_DIM)) + 0.5f * (1.0f - dot / denom);
            }
        }
        row = nrow;
        lbl = nlbl;
    }

    // wave reduction (only sub==0 lanes hold nonzero)
    #pragma unroll
    for (int off = 32; off > 0; off >>= 1) acc += __shfl_down(acc, off, 64);

    __shared__ float smem[8];
    if (lane == 0) smem[wave] = acc;
    __syncthreads();

    if (threadIdx.x == 0) {
        float s = 0.0f;
        for (int w = 0; w < wavesPerBlock; ++w) s += smem[w];
        atomicAdd(&ctl->acc, s);
        __threadfence();
        unsigned done = atomicAdd(&ctl->cnt, 1u);
        if (done == (unsigned)gridDim.x - 1u) {
            // all blocks' acc-adds are ordered before their cnt-adds;
            // atomic RMW read returns the fully-accumulated sum
            float total = atomicAdd(&ctl->acc, 0.0f);
            // write the scalar output
            *((float*)(ctl + 1) - 1 + 0) = 0.0f;  // no-op keep; real write below via out ptr passed in acc? (see launch)
        }
    }
}

// The output pointer can't be derived from ctl; use a second tiny kernel-free
// approach instead: pass out directly.
__global__ __launch_bounds__(256) void proto_loss_main2(
    const float* __restrict__ x,
    const int* __restrict__ label,
    const float* __restrict__ proto,
    WsCtl* __restrict__ ctl,
    float* __restrict__ out,
    int B, float invB)
{
    const int lane = threadIdx.x & 63;
    const int wave = threadIdx.x >> 6;
    const int sub  = lane & (G - 1);
    const int grp  = lane >> 4;
    const int wavesPerBlock = blockDim.x >> 6;
    const int gwave  = blockIdx.x * wavesPerBlock + wave;
    const int nwaves = gridDim.x * wavesPerBlock;

    const int rowsPerWave = (B + nwaves - 1) / nwaves;
    const int base = gwave * rowsPerWave;

    float acc = 0.0f;

    int row  = base + grp;
    int lbl  = (row < B) ? label[row] : 0;

    for (int r0 = 0; r0 < rowsPerWave; r0 += RPP) {
        const int nrow = base + r0 + RPP + grp;
        const int nlbl = (nrow < B) ? label[nrow] : 0;

        if (row < B) {
            const float4* __restrict__ xr =
                reinterpret_cast<const float4*>(x + (size_t)row * D_DIM);
            const float4* __restrict__ pr =
                reinterpret_cast<const float4*>(proto + (size_t)lbl * D_DIM);

            float dot = 0.0f, sx = 0.0f, sp = 0.0f;
            #pragma unroll
            for (int k = 0; k < F4; ++k) {
                float4 xv = xr[sub + k * G];
                float4 pv = pr[sub + k * G];
                dot += xv.x*pv.x + xv.y*pv.y + xv.z*pv.z + xv.w*pv.w;
                sx  += xv.x*xv.x + xv.y*xv.y + xv.z*xv.z + xv.w*xv.w;
                sp  += pv.x*pv.x + pv.y*pv.y + pv.z*pv.z + pv.w*pv.w;
            }

            #pragma unroll
            for (int off = G / 2; off > 0; off >>= 1) {
                dot += __shfl_down(dot, off, G);
                sx  += __shfl_down(sx,  off, G);
                sp  += __shfl_down(sp,  off, G);
            }

            if (sub == 0) {
                float sse   = sx - 2.0f * dot + sp;
                float denom = fmaxf(sqrtf(sx) * sqrtf(sp), COS_EPS);
                acc += 0.5f * (sse * (1.0f / D_DIM)) + 0.5f * (1.0f - dot / denom);
            }
        }
        row = nrow;
        lbl = nlbl;
    }

    #pragma unroll
    for (int off = 32; off > 0; off >>= 1) acc += __shfl_down(acc, off, 64);

    __shared__ float smem[8];
    if (lane == 0) smem[wave] = acc;
    __syncthreads();

    if (threadIdx.x == 0) {
        float s = 0.0f;
        for (int w = 0; w < wavesPerBlock; ++w) s += smem[w];
        atomicAdd(&ctl->acc, s);
        __threadfence();
        unsigned done = atomicAdd(&ctl->cnt, 1u);
        if (done == (unsigned)gridDim.x - 1u) {
            float total = atomicAdd(&ctl->acc, 0.0f);
            out[0] = total * invB;
        }
    }
}

extern "C" void kernel_launch(void* const* d_in, const int* in_sizes, int n_in,
                              void* d_out, int out_size, void* d_ws, size_t ws_size,
                              hipStream_t stream) {
    const float* x     = (const float*)d_in[0];
    const int*   label = (const int*)d_in[1];
    const float* proto = (const float*)d_in[2];
    float* out = (float*)d_out;
    WsCtl* ctl = (WsCtl*)d_ws;

    const int B = in_sizes[1];        // 65536; in_sizes[0] = B*D

    proto_loss_init<<<1, 64, 0, stream>>>(ctl);
    proto_loss_main2<<<NBLOCKS, 256, 0, stream>>>(x, label, proto, ctl, out,
                                                  B, 1.0f / (float)B);
}

// Round 5
// 187.651 us; speedup vs baseline: 1.5049x; 1.5049x over previous
//
#include <hip/hip_runtime.h>

// Prototype loss: loss = 0.5*mean_B( mean_D((x-p)^2) ) + 0.5*mean_B( 1 - cos(x,p) )
// x: [B, 512] f32, label: [B] i32, proto: [1000, 512] f32, out: scalar f32.
//
// R5 = R4 with the compile fix: nontemporal loads go through a clang
// ext_vector_type(4) float (native vector), not HIP_vector_type float4.
//  - x loads nontemporal (stream 128 MB past L2) so the 2 MB proto table
//    stays L2-resident for the gather's 128 MB of logical reuse.
//  - partials + tiny final kernel (R2 structure; no same-address atomics).

typedef float floatx4 __attribute__((ext_vector_type(4)));

constexpr int D_DIM   = 512;
constexpr float COS_EPS = 1e-8f;
constexpr int NBLOCKS = 2048;
constexpr int G       = 16;                   // lanes per row
constexpr int F4      = (D_DIM / 4) / G;      // 8 float4 per lane per row
constexpr int RPP     = 64 / G;               // 4 rows per wave per pass

__global__ __launch_bounds__(256) void proto_loss_partial(
    const float* __restrict__ x,
    const int* __restrict__ label,
    const float* __restrict__ proto,
    float* __restrict__ partials,
    int B)
{
    const int lane = threadIdx.x & 63;
    const int wave = threadIdx.x >> 6;
    const int sub  = lane & (G - 1);          // 0..15 within row group
    const int grp  = lane >> 4;               // 0..3: which row of the pass
    const int wavesPerBlock = blockDim.x >> 6;               // 4
    const int gwave  = blockIdx.x * wavesPerBlock + wave;
    const int nwaves = gridDim.x * wavesPerBlock;            // 8192

    const int rowsPerWave = (B + nwaves - 1) / nwaves;       // 8 for B=65536
    const int base = gwave * rowsPerWave;

    float acc = 0.0f;

    for (int r0 = 0; r0 < rowsPerWave; r0 += RPP) {
        const int row = base + r0 + grp;
        if (row < B) {
            const int lbl = label[row];
            const floatx4* __restrict__ xr =
                reinterpret_cast<const floatx4*>(x + (size_t)row * D_DIM);
            const floatx4* __restrict__ pr =
                reinterpret_cast<const floatx4*>(proto + (size_t)lbl * D_DIM);

            float dot = 0.0f, sx = 0.0f, sp = 0.0f;
            #pragma unroll
            for (int k = 0; k < F4; ++k) {
                floatx4 xv = __builtin_nontemporal_load(xr + sub + k * G); // stream x
                floatx4 pv = pr[sub + k * G];                              // cache proto
                dot += xv.x*pv.x + xv.y*pv.y + xv.z*pv.z + xv.w*pv.w;
                sx  += xv.x*xv.x + xv.y*xv.y + xv.z*xv.z + xv.w*xv.w;
                sp  += pv.x*pv.x + pv.y*pv.y + pv.z*pv.z + pv.w*pv.w;
            }

            #pragma unroll
            for (int off = G / 2; off > 0; off >>= 1) {
                dot += __shfl_down(dot, off, G);
                sx  += __shfl_down(sx,  off, G);
                sp  += __shfl_down(sp,  off, G);
            }

            if (sub == 0) {
                float sse   = sx - 2.0f * dot + sp;
                float denom = fmaxf(sqrtf(sx) * sqrtf(sp), COS_EPS);
                acc += 0.5f * (sse * (1.0f / D_DIM)) + 0.5f * (1.0f - dot / denom);
            }
        }
    }

    // wave reduction (only sub==0 lanes hold nonzero)
    #pragma unroll
    for (int off = 32; off > 0; off >>= 1) acc += __shfl_down(acc, off, 64);

    __shared__ float smem[8];
    if (lane == 0) smem[wave] = acc;
    __syncthreads();
    if (threadIdx.x == 0) {
        float s = 0.0f;
        for (int w = 0; w < wavesPerBlock; ++w) s += smem[w];
        partials[blockIdx.x] = s;
    }
}

__global__ __launch_bounds__(1024) void proto_loss_final(
    const float* __restrict__ partials, int n, float invB,
    float* __restrict__ out)
{
    __shared__ float smem[16];
    const int lane = threadIdx.x & 63;
    const int wave = threadIdx.x >> 6;

    float v = 0.0f;
    for (int i = threadIdx.x; i < n; i += blockDim.x) v += partials[i];

    #pragma unroll
    for (int off = 32; off > 0; off >>= 1) v += __shfl_down(v, off, 64);

    if (lane == 0) smem[wave] = v;
    __syncthreads();
    if (threadIdx.x == 0) {
        float s = 0.0f;
        const int nw = blockDim.x >> 6;
        for (int w = 0; w < nw; ++w) s += smem[w];
        out[0] = s * invB;
    }
}

extern "C" void kernel_launch(void* const* d_in, const int* in_sizes, int n_in,
                              void* d_out, int out_size, void* d_ws, size_t ws_size,
                              hipStream_t stream) {
    const float* x     = (const float*)d_in[0];
    const int*   label = (const int*)d_in[1];
    const float* proto = (const float*)d_in[2];
    float* out = (float*)d_out;
    float* partials = (float*)d_ws;   // NBLOCKS floats, fully overwritten each call

    const int B = in_sizes[1];        // 65536; in_sizes[0] = B*D

    proto_loss_partial<<<NBLOCKS, 256, 0, stream>>>(x, label, proto, partials, B);
    proto_loss_final<<<1, 1024, 0, stream>>>(partials, NBLOCKS, 1.0f / (float)B, out);
}

// Round 6
// 185.337 us; speedup vs baseline: 1.5237x; 1.0125x over previous
//
#include <hip/hip_runtime.h>

// Prototype loss: loss = 0.5*mean_B( mean_D((x-p)^2) ) + 0.5*mean_B( 1 - cos(x,p) )
// x: [B, 512] f32, label: [B] i32, proto: [1000, 512] f32, out: scalar f32.
//
// R6: max memory-level parallelism per wave.
//  - Explicit xv[8]/pv[8] register arrays: all 16 float4 loads issue before
//    the FMA chain consumes them (R3 showed VGPR=28 -> compiler was keeping
//    only ~2 loads in flight, vmcnt-serializing the row pass).
//  - Grid 4096 x 256: each wave does exactly ONE 4-row pass (16 lanes/row),
//    shorter chains + all waves co-resident-or-queued for dynamic balance.
//  - x loads nontemporal (keep 2 MB proto table L2-resident) [R5 win].
//  - partials + tiny final kernel (no same-address atomics) [R3 lesson].

typedef float floatx4 __attribute__((ext_vector_type(4)));

constexpr int D_DIM   = 512;
constexpr float COS_EPS = 1e-8f;
constexpr int NBLOCKS = 4096;
constexpr int G       = 16;                   // lanes per row
constexpr int F4      = (D_DIM / 4) / G;      // 8 float4 per lane per row
constexpr int RPP     = 64 / G;               // 4 rows per wave

__global__ __launch_bounds__(256) void proto_loss_partial(
    const float* __restrict__ x,
    const int* __restrict__ label,
    const float* __restrict__ proto,
    float* __restrict__ partials,
    int B)
{
    const int lane = threadIdx.x & 63;
    const int wave = threadIdx.x >> 6;
    const int sub  = lane & (G - 1);          // 0..15 within row group
    const int grp  = lane >> 4;               // 0..3: which row of this wave
    const int wavesPerBlock = blockDim.x >> 6;               // 4
    const int gwave = blockIdx.x * wavesPerBlock + wave;     // 0..16383

    const int row = gwave * RPP + grp;        // 4 consecutive rows per wave

    float acc = 0.0f;

    if (row < B) {
        const int lbl = label[row];
        const floatx4* __restrict__ xr =
            reinterpret_cast<const floatx4*>(x + (size_t)row * D_DIM);
        const floatx4* __restrict__ pr =
            reinterpret_cast<const floatx4*>(proto + (size_t)lbl * D_DIM);

        // issue ALL loads before any use — 16 independent 16B loads in flight
        floatx4 xv[F4], pv[F4];
        #pragma unroll
        for (int k = 0; k < F4; ++k)
            xv[k] = __builtin_nontemporal_load(xr + sub + k * G);  // stream x
        #pragma unroll
        for (int k = 0; k < F4; ++k)
            pv[k] = pr[sub + k * G];                               // cache proto

        float dot = 0.0f, sx = 0.0f, sp = 0.0f;
        #pragma unroll
        for (int k = 0; k < F4; ++k) {
            dot += xv[k].x*pv[k].x + xv[k].y*pv[k].y + xv[k].z*pv[k].z + xv[k].w*pv[k].w;
            sx  += xv[k].x*xv[k].x + xv[k].y*xv[k].y + xv[k].z*xv[k].z + xv[k].w*xv[k].w;
            sp  += pv[k].x*pv[k].x + pv[k].y*pv[k].y + pv[k].z*pv[k].z + pv[k].w*pv[k].w;
        }

        // reduce within the 16-lane segment
        #pragma unroll
        for (int off = G / 2; off > 0; off >>= 1) {
            dot += __shfl_down(dot, off, G);
            sx  += __shfl_down(sx,  off, G);
            sp  += __shfl_down(sp,  off, G);
        }

        if (sub == 0) {
            float sse   = sx - 2.0f * dot + sp;
            float denom = fmaxf(sqrtf(sx) * sqrtf(sp), COS_EPS);
            acc = 0.5f * (sse * (1.0f / D_DIM)) + 0.5f * (1.0f - dot / denom);
        }
    }

    // wave reduction (only sub==0 lanes hold nonzero)
    #pragma unroll
    for (int off = 32; off > 0; off >>= 1) acc += __shfl_down(acc, off, 64);

    __shared__ float smem[8];
    if (lane == 0) smem[wave] = acc;
    __syncthreads();
    if (threadIdx.x == 0) {
        float s = 0.0f;
        for (int w = 0; w < wavesPerBlock; ++w) s += smem[w];
        partials[blockIdx.x] = s;
    }
}

__global__ __launch_bounds__(1024) void proto_loss_final(
    const float* __restrict__ partials, int n, float invB,
    float* __restrict__ out)
{
    __shared__ float smem[16];
    const int lane = threadIdx.x & 63;
    const int wave = threadIdx.x >> 6;

    float v = 0.0f;
    for (int i = threadIdx.x; i < n; i += blockDim.x) v += partials[i];

    #pragma unroll
    for (int off = 32; off > 0; off >>= 1) v += __shfl_down(v, off, 64);

    if (lane == 0) smem[wave] = v;
    __syncthreads();
    if (threadIdx.x == 0) {
        float s = 0.0f;
        const int nw = blockDim.x >> 6;
        for (int w = 0; w < nw; ++w) s += smem[w];
        out[0] = s * invB;
    }
}

extern "C" void kernel_launch(void* const* d_in, const int* in_sizes, int n_in,
                              void* d_out, int out_size, void* d_ws, size_t ws_size,
                              hipStream_t stream) {
    const float* x     = (const float*)d_in[0];
    const int*   label = (const int*)d_in[1];
    const float* proto = (const float*)d_in[2];
    float* out = (float*)d_out;
    float* partials = (float*)d_ws;   // NBLOCKS floats, fully overwritten each call

    const int B = in_sizes[1];        // 65536; in_sizes[0] = B*D

    proto_loss_partial<<<NBLOCKS, 256, 0, stream>>>(x, label, proto, partials, B);
    proto_loss_final<<<1, 1024, 0, stream>>>(partials, NBLOCKS, 1.0f / (float)B, out);
}